// Round 4
// baseline (2470.655 us; speedup 1.0000x reference)
//
#include <hip/hip_runtime.h>
#include <stdint.h>
#include <stddef.h>

// ---------- types / helpers ----------
typedef __attribute__((ext_vector_type(8))) short  short8;   // 8 bf16 (4 VGPRs)
typedef __attribute__((ext_vector_type(4))) float  floatx4;  // MFMA acc
typedef __attribute__((ext_vector_type(4))) unsigned int u32x4; // 16B poll frag
typedef unsigned long long u64;

#define SENT 0xAAAAAAAAAAAAAAAAull   // ws poison pattern = our sentinel

static __device__ __forceinline__ float b2f(uint16_t h) {
  union { uint32_t u; float f; } v; v.u = ((uint32_t)h) << 16; return v.f;
}
static __device__ __forceinline__ uint16_t f2b(float f) {
  union { float f; uint32_t u; } v; v.f = f;
  uint32_t u = v.u;
  uint32_t r = u + 0x7FFFu + ((u >> 16) & 1u);   // RNE
  return (uint16_t)(r >> 16);
}
static __device__ __forceinline__ float sigm(float x)  { return 1.0f / (1.0f + __expf(-x)); }
static __device__ __forceinline__ float tanh_f(float x){ return 1.0f - 2.0f / (1.0f + __expf(2.0f * x)); }

static __device__ __forceinline__ floatx4 mfma16(short8 a, short8 b, floatx4 c) {
  return __builtin_amdgcn_mfma_f32_16x16x32_bf16(a, b, c, 0, 0, 0);
}
static __device__ __forceinline__ short8 cvt8(const float* p) {
  short8 r;
  #pragma unroll
  for (int i = 0; i < 8; ++i) r[i] = (short)f2b(p[i]);
  return r;
}

// ---------- exchange primitives ----------
// Stores: round-0/3-proven agent-scope atomic store (any placement).
static __device__ __forceinline__ void st_h64(uint16_t* p, u64 v) {
  __hip_atomic_store((u64*)p, v, __ATOMIC_RELAXED, __HIP_MEMORY_SCOPE_AGENT);
}
static __device__ __forceinline__ u64 ld_h64(const u64* p) {
  return __hip_atomic_load(p, __ATOMIC_RELAXED, __HIP_MEMORY_SCOPE_AGENT);
}
// Direct-to-register fragment poll (round-3-proven asm path, widened to
// dwordx4): each lane polls EXACTLY its MFMA B-fragments — 8 (enc) or 16
// (dec) 16B chunks at 64B stride — in ONE asm block, ONE vmcnt(0).
// sc0 sc1 = system scope (bypass L1+L2), correct for any block->XCD
// placement. Each 16B frag spans TWO producer threads' 8B stores, so both
// u64 halves are sentinel-checked.
static __device__ __forceinline__ bool frag_ok(u32x4 v) {
  const u64 lo = ((u64)v[1] << 32) | v[0];
  const u64 hi = ((u64)v[3] << 32) | v[2];
  return (lo != SENT) & (hi != SENT);
}
static __device__ __forceinline__ void ld8x16(const uint16_t* p, u32x4* o) {
  asm volatile(
      "global_load_dwordx4 %0, %8, off sc0 sc1\n\t"
      "global_load_dwordx4 %1, %8, off offset:64 sc0 sc1\n\t"
      "global_load_dwordx4 %2, %8, off offset:128 sc0 sc1\n\t"
      "global_load_dwordx4 %3, %8, off offset:192 sc0 sc1\n\t"
      "global_load_dwordx4 %4, %8, off offset:256 sc0 sc1\n\t"
      "global_load_dwordx4 %5, %8, off offset:320 sc0 sc1\n\t"
      "global_load_dwordx4 %6, %8, off offset:384 sc0 sc1\n\t"
      "global_load_dwordx4 %7, %8, off offset:448 sc0 sc1\n\t"
      "s_waitcnt vmcnt(0)"
      : "=&v"(o[0]), "=&v"(o[1]), "=&v"(o[2]), "=&v"(o[3]),
        "=&v"(o[4]), "=&v"(o[5]), "=&v"(o[6]), "=&v"(o[7])
      : "v"(p)
      : "memory");
}
static __device__ __forceinline__ void ld16x16(const uint16_t* pa, const uint16_t* pb,
                                               u32x4* oa, u32x4* ob) {
  asm volatile(
      "global_load_dwordx4 %0, %16, off sc0 sc1\n\t"
      "global_load_dwordx4 %1, %16, off offset:64 sc0 sc1\n\t"
      "global_load_dwordx4 %2, %16, off offset:128 sc0 sc1\n\t"
      "global_load_dwordx4 %3, %16, off offset:192 sc0 sc1\n\t"
      "global_load_dwordx4 %4, %16, off offset:256 sc0 sc1\n\t"
      "global_load_dwordx4 %5, %16, off offset:320 sc0 sc1\n\t"
      "global_load_dwordx4 %6, %16, off offset:384 sc0 sc1\n\t"
      "global_load_dwordx4 %7, %16, off offset:448 sc0 sc1\n\t"
      "global_load_dwordx4 %8, %17, off sc0 sc1\n\t"
      "global_load_dwordx4 %9, %17, off offset:64 sc0 sc1\n\t"
      "global_load_dwordx4 %10, %17, off offset:128 sc0 sc1\n\t"
      "global_load_dwordx4 %11, %17, off offset:192 sc0 sc1\n\t"
      "global_load_dwordx4 %12, %17, off offset:256 sc0 sc1\n\t"
      "global_load_dwordx4 %13, %17, off offset:320 sc0 sc1\n\t"
      "global_load_dwordx4 %14, %17, off offset:384 sc0 sc1\n\t"
      "global_load_dwordx4 %15, %17, off offset:448 sc0 sc1\n\t"
      "s_waitcnt vmcnt(0)"
      : "=&v"(oa[0]), "=&v"(oa[1]), "=&v"(oa[2]), "=&v"(oa[3]),
        "=&v"(oa[4]), "=&v"(oa[5]), "=&v"(oa[6]), "=&v"(oa[7]),
        "=&v"(ob[0]), "=&v"(ob[1]), "=&v"(ob[2]), "=&v"(ob[3]),
        "=&v"(ob[4]), "=&v"(ob[5]), "=&v"(ob[6]), "=&v"(ob[7])
      : "v"(pa), "v"(pb)
      : "memory");
}
static __device__ __forceinline__ void valve8(const uint16_t* p, u32x4* o) {
  const u64* q = (const u64*)p;
  #pragma unroll
  for (int k = 0; k < 8; ++k) {
    u64 a = ld_h64(q + k * 8), c = ld_h64(q + k * 8 + 1);
    o[k][0] = (unsigned)a; o[k][1] = (unsigned)(a >> 32);
    o[k][2] = (unsigned)c; o[k][3] = (unsigned)(c >> 32);
  }
}
// Poll with safety valve: every 1024th pass uses the round-0-proven atomic
// loads, so a misbehaving asm path degrades latency instead of hanging.
static __device__ __forceinline__ void poll8f(const uint16_t* p, u32x4* o) {
  int it = 0;
  for (;;) {
    if ((++it & 1023) == 0) valve8(p, o); else ld8x16(p, o);
    bool ok = true;
    #pragma unroll
    for (int k = 0; k < 8; ++k) ok &= frag_ok(o[k]);
    if (ok) break;
    __builtin_amdgcn_s_sleep(1);
  }
}
static __device__ __forceinline__ void poll16f(const uint16_t* pa, const uint16_t* pb,
                                               u32x4* oa, u32x4* ob) {
  int it = 0;
  for (;;) {
    if ((++it & 1023) == 0) { valve8(pa, oa); valve8(pb, ob); }
    else ld16x16(pa, pb, oa, ob);
    bool ok = true;
    #pragma unroll
    for (int k = 0; k < 8; ++k) ok &= frag_ok(oa[k]) & frag_ok(ob[k]);
    if (ok) break;
    __builtin_amdgcn_s_sleep(1);
  }
}

#define H 256
#define FH 1024
#define BATCH 32
#define TSEQ 512
#define DSTEPS 64
#define ERING 8

// =====================================================================
// Phase A GEMM (unchanged — verified)
// =====================================================================
__global__ __launch_bounds__(256) void gemm_xw(
    const float* __restrict__ A, const float* __restrict__ W,
    const float* __restrict__ bias, void* __restrict__ Cout, int out_f32)
{
  const int K = 1024, N = 1024;
  __shared__ uint16_t Ah[64 * 40], Al[64 * 40];
  __shared__ uint16_t Wh[64 * 40], Wl[64 * 40];
  const int m0 = blockIdx.x * 64;
  const int n0 = blockIdx.y * 64;
  const int tid = threadIdx.x;
  const int lane = tid & 63, w = tid >> 6;
  const int wm = w & 1, wn = w >> 1;
  const int l15 = lane & 15, q4 = lane >> 4;
  const int ldrow = tid >> 2, ldk = (tid & 3) * 8;

  floatx4 acc[2][2];
  for (int i = 0; i < 2; ++i) for (int j = 0; j < 2; ++j) acc[i][j] = (floatx4){0.f,0.f,0.f,0.f};

  for (int kb = 0; kb < K; kb += 32) {
    float aa[8], ww[8];
    {
      const float4* ap = (const float4*)(A + (size_t)(m0 + ldrow) * K + kb + ldk);
      const float4* wp = (const float4*)(W + (size_t)(n0 + ldrow) * K + kb + ldk);
      *(float4*)(aa) = ap[0]; *(float4*)(aa + 4) = ap[1];
      *(float4*)(ww) = wp[0]; *(float4*)(ww + 4) = wp[1];
    }
    short8 ah, al, wh, wl;
    #pragma unroll
    for (int i = 0; i < 8; ++i) {
      uint16_t h = f2b(aa[i]); ah[i] = (short)h; al[i] = (short)f2b(aa[i] - b2f(h));
      uint16_t g = f2b(ww[i]); wh[i] = (short)g; wl[i] = (short)f2b(ww[i] - b2f(g));
    }
    __syncthreads();
    *(short8*)(Ah + ldrow * 40 + ldk) = ah;
    *(short8*)(Al + ldrow * 40 + ldk) = al;
    *(short8*)(Wh + ldrow * 40 + ldk) = wh;
    *(short8*)(Wl + ldrow * 40 + ldk) = wl;
    __syncthreads();
    short8 afh[2], afl[2], bfh[2], bfl[2];
    #pragma unroll
    for (int mt = 0; mt < 2; ++mt) {
      afh[mt] = *(const short8*)(Ah + (wm * 32 + mt * 16 + l15) * 40 + q4 * 8);
      afl[mt] = *(const short8*)(Al + (wm * 32 + mt * 16 + l15) * 40 + q4 * 8);
    }
    #pragma unroll
    for (int nt = 0; nt < 2; ++nt) {
      bfh[nt] = *(const short8*)(Wh + (wn * 32 + nt * 16 + l15) * 40 + q4 * 8);
      bfl[nt] = *(const short8*)(Wl + (wn * 32 + nt * 16 + l15) * 40 + q4 * 8);
    }
    #pragma unroll
    for (int mt = 0; mt < 2; ++mt)
      #pragma unroll
      for (int nt = 0; nt < 2; ++nt) {
        acc[mt][nt] = mfma16(afh[mt], bfh[nt], acc[mt][nt]);
        acc[mt][nt] = mfma16(afh[mt], bfl[nt], acc[mt][nt]);
        acc[mt][nt] = mfma16(afl[mt], bfh[nt], acc[mt][nt]);
      }
  }
  #pragma unroll
  for (int mt = 0; mt < 2; ++mt)
    #pragma unroll
    for (int nt = 0; nt < 2; ++nt) {
      const int col = n0 + wn * 32 + nt * 16 + l15;
      const float bv = bias[col];
      #pragma unroll
      for (int r = 0; r < 4; ++r) {
        const int row = m0 + wm * 32 + mt * 16 + q4 * 4 + r;
        const float v = acc[mt][nt][r] + bv;
        if (out_f32) ((float*)Cout)[(size_t)row * N + col] = v;
        else         ((uint16_t*)Cout)[(size_t)row * N + col] = f2b(v);
      }
    }
}

// =====================================================================
// Phase B: encoder recurrence, BARRIER-FREE. Grid = 16 WGs: d=blk>>3,
// q=blk&7. The LSTM recurrence is row-independent (h row b depends only
// on h row b), and each lane's MFMA B-fragment is 8x16B of its own row:
// h[b][ks*32+q4*8 .. +8]. So each lane polls its fragments DIRECTLY into
// registers (polled u32x4 == short8 operand) — no LDS, no __syncthreads,
// waves free-run bounded only by data deps. Xg gate values are per-lane
// owned too -> loaded directly, prefetched one step ahead.
// Re-poison at distance 6 (no barrier): the row-b dep graph (consumer q4
// <- producers tt'=q4>>1, q4' in {2(q4&1),2(q4&1)+1}, all 8 WGs) reaches
// every (tt,q4,WG) class in <=3 hops => when a thread starts step s, all
// row-b threads have completed polling slot s-4; distance 6 has margin.
// Poison(s-6 == s+2 mod 8) -> produce(s+2) same-thread same-address order
// is enforced by the two intervening polls' vmcnt(0) drains.
// =====================================================================
__global__ __launch_bounds__(256, 1) void enc_rnn(
    const void* __restrict__ XgF, const void* __restrict__ XgB, int xg_f32,
    const float* __restrict__ WhhF, const float* __restrict__ WhhB,
    uint16_t* __restrict__ hslots,    // [2 dir][ERING][32][256] bf16, poisoned
    uint16_t* __restrict__ hfin, float* __restrict__ cfin)
{
  const int d = blockIdx.x >> 3, q = blockIdx.x & 7;
  const void*  Xg  = d ? XgB : XgF;
  const float* Whh = d ? WhhB : WhhF;
  uint16_t* hsl = hslots + d * (ERING * BATCH * H);
  const int jOff = q * 32;
  const int tid = threadIdx.x, lane = tid & 63, w = tid >> 6;
  const int tt = w & 1, nt = w >> 1, l15 = lane & 15, q4 = lane >> 4;
  const int b = nt * 16 + l15;
  const int jg = jOff + tt * 16 + q4 * 4;

  short8 Af[4][8];
  #pragma unroll
  for (int g = 0; g < 4; ++g) {
    const int grow = g * H + jOff + tt * 16 + l15;
    #pragma unroll
    for (int ks = 0; ks < 8; ++ks)
      Af[g][ks] = cvt8(Whh + (size_t)grow * H + ks * 32 + q4 * 8);
  }

  float cc[4] = {0.f, 0.f, 0.f, 0.f};
  union HV { uint16_t u16[4]; u64 v; } hv; hv.v = 0ull;

  // per-lane Xg gate slice: [(t*B+b)*FH + g*H + jg], g=0..3 (16B f32 / 8B bf16)
  float xvf[16];
  u64   xvb[4];
  auto ldx = [&](int s2) {
    const int t2 = d ? (TSEQ - 1 - s2) : s2;
    const size_t bas = (size_t)(t2 * BATCH + b) * FH + jg;
    if (xg_f32) {
      const float* xp = (const float*)Xg + bas;
      *(float4*)(xvf + 0)  = *(const float4*)(xp);
      *(float4*)(xvf + 4)  = *(const float4*)(xp + H);
      *(float4*)(xvf + 8)  = *(const float4*)(xp + 2 * H);
      *(float4*)(xvf + 12) = *(const float4*)(xp + 3 * H);
    } else {
      const uint16_t* xp = (const uint16_t*)Xg + bas;
      xvb[0] = *(const u64*)(xp);
      xvb[1] = *(const u64*)(xp + H);
      xvb[2] = *(const u64*)(xp + 2 * H);
      xvb[3] = *(const u64*)(xp + 3 * H);
    }
  };
  ldx(0);

  for (int s = 0; s < TSEQ; ++s) {
    floatx4 a0 = {0.f,0.f,0.f,0.f}, a1 = a0, a2 = a0, a3 = a0;
    if (s > 0) {
      u32x4 pol[8];
      const uint16_t* ps = hsl + ((s - 1) & (ERING - 1)) * (BATCH * H) + b * H + q4 * 8;
      poll8f(ps, pol);
      #pragma unroll
      for (int ks = 0; ks < 8; ++ks) {
        short8 bfv = *(short8*)&pol[ks];
        a0 = mfma16(Af[0][ks], bfv, a0);
        a1 = mfma16(Af[1][ks], bfv, a1);
        a2 = mfma16(Af[2][ks], bfv, a2);
        a3 = mfma16(Af[3][ks], bfv, a3);
      }
    }
    #pragma unroll
    for (int r = 0; r < 4; ++r) {
      const float x0 = xg_f32 ? xvf[0 + r]  : b2f((uint16_t)(xvb[0] >> (16 * r)));
      const float x1 = xg_f32 ? xvf[4 + r]  : b2f((uint16_t)(xvb[1] >> (16 * r)));
      const float x2 = xg_f32 ? xvf[8 + r]  : b2f((uint16_t)(xvb[2] >> (16 * r)));
      const float x3 = xg_f32 ? xvf[12 + r] : b2f((uint16_t)(xvb[3] >> (16 * r)));
      const float gi = a0[r] + x0;
      const float gf = a1[r] + x1;
      const float gc = a2[r] + x2;
      const float go = a3[r] + x3;
      const float cn2 = sigm(gf) * cc[r] + sigm(gi) * tanh_f(gc);
      cc[r] = cn2;
      hv.u16[r] = f2b(sigm(go) * tanh_f(cn2));
    }
    st_h64(hsl + (s & (ERING - 1)) * (BATCH * H) + b * H + jg, hv.v);
    if (s >= 6)   // re-poison own slice at distance 6 (safe: see header)
      st_h64(hsl + ((s - 6) & (ERING - 1)) * (BATCH * H) + b * H + jg, SENT);
    if (s + 1 < TSEQ) ldx(s + 1);   // prefetch next step's Xg (after use)
  }
  #pragma unroll
  for (int r = 0; r < 4; ++r) {
    hfin[d * (BATCH * H) + b * H + jg + r] = hv.u16[r];   // kernel boundary
    cfin[d * (BATCH * H) + b * H + jg + r] = cc[r];
  }
}

// =====================================================================
// Phase C: decoder, BARRIER-FREE, same direct-fragment polling. Grid = 16
// WGs: L=blk>>3, q=blk&7. Write-once per-step slots (poisoned per launch,
// no runtime re-poison). Per lane: 16 B-fragments — ks 0..7 = x (cross
// layer) @ Wih, ks 8..15 = own-layer h @ Whh — polled jointly in one
// 16-load / one-vmcnt pass.
// =====================================================================
__global__ __launch_bounds__(256, 1) void dec_rnn(
    const float* __restrict__ Wih0, const float* __restrict__ Whh0, const float* __restrict__ bb0,
    const float* __restrict__ Wih1, const float* __restrict__ Whh1, const float* __restrict__ bb1,
    const uint16_t* __restrict__ hfin, const float* __restrict__ cfin,
    uint16_t* __restrict__ h0slots,  // [64][32][256] bf16, poisoned
    uint16_t* __restrict__ h1slots,  // [64][32][256] bf16, poisoned
    float*    __restrict__ h1f)      // [64][32][256] f32 (plain)
{
  const int L = blockIdx.x >> 3, q = blockIdx.x & 7;
  const float* Wih = L ? Wih1 : Wih0;
  const float* Whh = L ? Whh1 : Whh0;
  const float* bs  = L ? bb1 : bb0;
  const int jOff = q * 32;
  const int tid = threadIdx.x, lane = tid & 63, w = tid >> 6;
  const int tt = w & 1, nt = w >> 1, l15 = lane & 15, q4 = lane >> 4;
  const int b = nt * 16 + l15;
  const int jg = jOff + tt * 16 + q4 * 4;

  short8 Af[4][16];
  #pragma unroll
  for (int g = 0; g < 4; ++g) {
    const int grow = g * H + jOff + tt * 16 + l15;
    #pragma unroll
    for (int ks = 0; ks < 8; ++ks) {
      Af[g][ks]     = cvt8(Wih + (size_t)grow * H + ks * 32 + q4 * 8);
      Af[g][8 + ks] = cvt8(Whh + (size_t)grow * H + ks * 32 + q4 * 8);
    }
  }
  float brg[4][4];
  #pragma unroll
  for (int g = 0; g < 4; ++g)
    #pragma unroll
    for (int r = 0; r < 4; ++r)
      brg[g][r] = bs[g * H + jOff + tt * 16 + q4 * 4 + r];

  float cc[4];
  #pragma unroll
  for (int r = 0; r < 4; ++r) cc[r] = cfin[L * (BATCH * H) + b * H + jg + r];

  uint16_t*       hOwn = L ? h1slots : h0slots;
  const uint16_t* hX   = L ? h0slots : h1slots;
  const int fo = b * H + q4 * 8;   // per-lane fragment base (u16 units)
  union HV { uint16_t u16[4]; u64 v; } hv; hv.v = 0ull;

  for (int t = 0; t < DSTEPS; ++t) {
    u32x4 pol[16];   // 0..7 = x frags, 8..15 = own-h frags
    if (t == 0) {
      const uint16_t* ph = hfin + L * (BATCH * H) + fo;   // plain, kernel boundary
      #pragma unroll
      for (int k = 0; k < 8; ++k) pol[8 + k] = *(const u32x4*)(ph + k * 32);
      if (L == 0) {
        #pragma unroll
        for (int k = 0; k < 8; ++k) pol[k] = (u32x4){0u, 0u, 0u, 0u};
      } else {
        poll8f(hX + fo, pol);                             // x = h0[t=0]
      }
    } else {
      const uint16_t* pOwn = hOwn + (size_t)(t - 1) * (BATCH * H) + fo;
      const uint16_t* pX   = L ? (hX + (size_t)t * (BATCH * H) + fo)        // h0[t]
                               : (hX + (size_t)(t - 1) * (BATCH * H) + fo); // h1[t-1]
      poll16f(pX, pOwn, pol, pol + 8);
    }

    floatx4 a0 = {0.f,0.f,0.f,0.f}, a1 = a0, a2 = a0, a3 = a0;
    #pragma unroll
    for (int ks = 0; ks < 16; ++ks) {
      short8 bfv = *(short8*)&pol[ks];
      a0 = mfma16(Af[0][ks], bfv, a0);
      a1 = mfma16(Af[1][ks], bfv, a1);
      a2 = mfma16(Af[2][ks], bfv, a2);
      a3 = mfma16(Af[3][ks], bfv, a3);
    }
    float hval[4];
    #pragma unroll
    for (int r = 0; r < 4; ++r) {
      const float gi = a0[r] + brg[0][r];
      const float gf = a1[r] + brg[1][r];
      const float gc = a2[r] + brg[2][r];
      const float go = a3[r] + brg[3][r];
      const float cn2 = sigm(gf) * cc[r] + sigm(gi) * tanh_f(gc);
      cc[r] = cn2;
      hval[r] = sigm(go) * tanh_f(cn2);
      hv.u16[r] = f2b(hval[r]);
    }
    st_h64(hOwn + (size_t)t * (BATCH * H) + b * H + jg, hv.v);
    if (L == 1) {
      float* df = h1f + (size_t)t * (BATCH * H) + b * H + jg;
      #pragma unroll
      for (int r = 0; r < 4; ++r) df[r] = hval[r];
    }
  }
}

// =====================================================================
// Phase D
// =====================================================================
__global__ __launch_bounds__(256) void out_proj(
    const float* __restrict__ h1f, const float* __restrict__ linW,
    const float* __restrict__ linb, float* __restrict__ out)
{
  const int idx = blockIdx.x * 256 + threadIdx.x;
  if (idx >= DSTEPS * BATCH * 3) return;
  const int v = idx % 3;
  const int tb = idx / 3;
  const float* hrow = h1f + (size_t)tb * H;
  const float* wrow = linW + (size_t)v * H;
  float s = linb[v];
  for (int k = 0; k < H; ++k) s += hrow[k] * wrow[k];
  out[idx] = s;
}

// =====================================================================
extern "C" void kernel_launch(void* const* d_in, const int* in_sizes, int n_in,
                              void* d_out, int out_size, void* d_ws, size_t ws_size,
                              hipStream_t stream) {
  (void)in_sizes; (void)n_in; (void)out_size;
  const float* cnn   = (const float*)d_in[0];
  const float* WihF  = (const float*)d_in[1];
  const float* WhhF  = (const float*)d_in[2];
  const float* bF    = (const float*)d_in[3];
  const float* WihB  = (const float*)d_in[4];
  const float* WhhB  = (const float*)d_in[5];
  const float* bB    = (const float*)d_in[6];
  const float* Wih0  = (const float*)d_in[7];
  const float* Whh0  = (const float*)d_in[8];
  const float* b0    = (const float*)d_in[9];
  const float* Wih1  = (const float*)d_in[10];
  const float* Whh1  = (const float*)d_in[11];
  const float* b1    = (const float*)d_in[12];
  const float* linW  = (const float*)d_in[13];
  const float* linb  = (const float*)d_in[14];

  const size_t XG_ELEMS = (size_t)TSEQ * BATCH * FH;   // 16 Mi elems / dir
  // small region: hslotsE 262144 | h0slots 1 MB | h1slots 1 MB | hfin 32K | cfin 64K
  const size_t SMALL = 2457600;
  const int xg_f32 = (ws_size >= 2 * XG_ELEMS * 4 + SMALL) ? 1 : 0;
  const size_t S = XG_ELEMS * (xg_f32 ? 4 : 2);

  uint8_t* ws = (uint8_t*)d_ws;
  void*     XgF    = (void*)(ws);
  void*     XgB    = (void*)(ws + S);
  float*    h1f    = (float*)(ws + S);                 // overlaps XgB: dead after enc
  uint8_t*  base   = ws + 2 * S;
  uint16_t* hslotsE = (uint16_t*)(base);               // 2*8*8192*2   = 262144
  uint16_t* h0slots = (uint16_t*)(base + 262144);      // 64*8192*2    = 1048576
  uint16_t* h1slots = (uint16_t*)(base + 1310720);     // 1048576  (poison end 2359296)
  uint16_t* hfin    = (uint16_t*)(base + 2359296);     // 32768
  float*    cfin    = (float*)(base + 2392064);        // 65536 (end 2457600)

  // sentinel-poison all exchange slots (required every launch, incl. replays)
  hipMemsetAsync(base, 0xAA, 2359296, stream);

  gemm_xw<<<dim3(256, 16), 256, 0, stream>>>(cnn, WihF, bF, XgF, xg_f32);
  gemm_xw<<<dim3(256, 16), 256, 0, stream>>>(cnn, WihB, bB, XgB, xg_f32);
  enc_rnn<<<16, 256, 0, stream>>>(XgF, XgB, xg_f32, WhhF, WhhB,
                                  hslotsE, hfin, cfin);
  dec_rnn<<<16, 256, 0, stream>>>(Wih0, Whh0, b0, Wih1, Whh1, b1,
                                  hfin, cfin, h0slots, h1slots, h1f);
  out_proj<<<24, 256, 0, stream>>>(h1f, linW, linb, (float*)d_out);
}

// Round 5
// 2345.115 us; speedup vs baseline: 1.0535x; 1.0535x over previous
//
#include <hip/hip_runtime.h>
#include <stdint.h>
#include <stddef.h>

// ---------- types / helpers ----------
typedef __attribute__((ext_vector_type(8))) short  short8;   // 8 bf16 (4 VGPRs)
typedef __attribute__((ext_vector_type(4))) float  floatx4;  // MFMA acc
typedef __attribute__((ext_vector_type(4))) unsigned int u32x4; // 16B poll frag
typedef unsigned long long u64;

#define SENT 0xAAAAAAAAAAAAAAAAull   // ws poison pattern = our sentinel

static __device__ __forceinline__ float b2f(uint16_t h) {
  union { uint32_t u; float f; } v; v.u = ((uint32_t)h) << 16; return v.f;
}
static __device__ __forceinline__ uint16_t f2b(float f) {
  union { float f; uint32_t u; } v; v.f = f;
  uint32_t u = v.u;
  uint32_t r = u + 0x7FFFu + ((u >> 16) & 1u);   // RNE
  return (uint16_t)(r >> 16);
}
static __device__ __forceinline__ float sigm(float x)  { return 1.0f / (1.0f + __expf(-x)); }
static __device__ __forceinline__ float tanh_f(float x){ return 1.0f - 2.0f / (1.0f + __expf(2.0f * x)); }

static __device__ __forceinline__ floatx4 mfma16(short8 a, short8 b, floatx4 c) {
  return __builtin_amdgcn_mfma_f32_16x16x32_bf16(a, b, c, 0, 0, 0);
}
static __device__ __forceinline__ short8 cvt8(const float* p) {
  short8 r;
  #pragma unroll
  for (int i = 0; i < 8; ++i) r[i] = (short)f2b(p[i]);
  return r;
}

// ---------- exchange primitives (r3/r4-proven) ----------
static __device__ __forceinline__ void st_h64(uint16_t* p, u64 v) {
  __hip_atomic_store((u64*)p, v, __ATOMIC_RELAXED, __HIP_MEMORY_SCOPE_AGENT);
}
static __device__ __forceinline__ u64 ld_h64(const u64* p) {
  return __hip_atomic_load(p, __ATOMIC_RELAXED, __HIP_MEMORY_SCOPE_AGENT);
}
static __device__ __forceinline__ bool frag_ok(u32x4 v) {
  const u64 lo = ((u64)v[1] << 32) | v[0];
  const u64 hi = ((u64)v[3] << 32) | v[2];
  return (lo != SENT) & (hi != SENT);
}
static __device__ __forceinline__ void ld8x16(const uint16_t* p, u32x4* o) {
  asm volatile(
      "global_load_dwordx4 %0, %8, off sc0 sc1\n\t"
      "global_load_dwordx4 %1, %8, off offset:64 sc0 sc1\n\t"
      "global_load_dwordx4 %2, %8, off offset:128 sc0 sc1\n\t"
      "global_load_dwordx4 %3, %8, off offset:192 sc0 sc1\n\t"
      "global_load_dwordx4 %4, %8, off offset:256 sc0 sc1\n\t"
      "global_load_dwordx4 %5, %8, off offset:320 sc0 sc1\n\t"
      "global_load_dwordx4 %6, %8, off offset:384 sc0 sc1\n\t"
      "global_load_dwordx4 %7, %8, off offset:448 sc0 sc1\n\t"
      "s_waitcnt vmcnt(0)"
      : "=&v"(o[0]), "=&v"(o[1]), "=&v"(o[2]), "=&v"(o[3]),
        "=&v"(o[4]), "=&v"(o[5]), "=&v"(o[6]), "=&v"(o[7])
      : "v"(p)
      : "memory");
}
static __device__ __forceinline__ void ld16x16(const uint16_t* pa, const uint16_t* pb,
                                               u32x4* oa, u32x4* ob) {
  asm volatile(
      "global_load_dwordx4 %0, %16, off sc0 sc1\n\t"
      "global_load_dwordx4 %1, %16, off offset:64 sc0 sc1\n\t"
      "global_load_dwordx4 %2, %16, off offset:128 sc0 sc1\n\t"
      "global_load_dwordx4 %3, %16, off offset:192 sc0 sc1\n\t"
      "global_load_dwordx4 %4, %16, off offset:256 sc0 sc1\n\t"
      "global_load_dwordx4 %5, %16, off offset:320 sc0 sc1\n\t"
      "global_load_dwordx4 %6, %16, off offset:384 sc0 sc1\n\t"
      "global_load_dwordx4 %7, %16, off offset:448 sc0 sc1\n\t"
      "global_load_dwordx4 %8, %17, off sc0 sc1\n\t"
      "global_load_dwordx4 %9, %17, off offset:64 sc0 sc1\n\t"
      "global_load_dwordx4 %10, %17, off offset:128 sc0 sc1\n\t"
      "global_load_dwordx4 %11, %17, off offset:192 sc0 sc1\n\t"
      "global_load_dwordx4 %12, %17, off offset:256 sc0 sc1\n\t"
      "global_load_dwordx4 %13, %17, off offset:320 sc0 sc1\n\t"
      "global_load_dwordx4 %14, %17, off offset:384 sc0 sc1\n\t"
      "global_load_dwordx4 %15, %17, off offset:448 sc0 sc1\n\t"
      "s_waitcnt vmcnt(0)"
      : "=&v"(oa[0]), "=&v"(oa[1]), "=&v"(oa[2]), "=&v"(oa[3]),
        "=&v"(oa[4]), "=&v"(oa[5]), "=&v"(oa[6]), "=&v"(oa[7]),
        "=&v"(ob[0]), "=&v"(ob[1]), "=&v"(ob[2]), "=&v"(ob[3]),
        "=&v"(ob[4]), "=&v"(ob[5]), "=&v"(ob[6]), "=&v"(ob[7])
      : "v"(pa), "v"(pb)
      : "memory");
}
static __device__ __forceinline__ void valve8(const uint16_t* p, u32x4* o) {
  const u64* q = (const u64*)p;
  #pragma unroll
  for (int k = 0; k < 8; ++k) {
    u64 a = ld_h64(q + k * 8), c = ld_h64(q + k * 8 + 1);
    o[k][0] = (unsigned)a; o[k][1] = (unsigned)(a >> 32);
    o[k][2] = (unsigned)c; o[k][3] = (unsigned)(c >> 32);
  }
}
static __device__ __forceinline__ void poll8f(const uint16_t* p, u32x4* o) {
  int it = 0;
  for (;;) {
    if ((++it & 1023) == 0) valve8(p, o); else ld8x16(p, o);
    bool ok = true;
    #pragma unroll
    for (int k = 0; k < 8; ++k) ok &= frag_ok(o[k]);
    if (ok) break;
    __builtin_amdgcn_s_sleep(1);
  }
}
static __device__ __forceinline__ void poll16f(const uint16_t* pa, const uint16_t* pb,
                                               u32x4* oa, u32x4* ob) {
  int it = 0;
  for (;;) {
    if ((++it & 1023) == 0) { valve8(pa, oa); valve8(pb, ob); }
    else ld16x16(pa, pb, oa, ob);
    bool ok = true;
    #pragma unroll
    for (int k = 0; k < 8; ++k) ok &= frag_ok(oa[k]) & frag_ok(ob[k]);
    if (ok) break;
    __builtin_amdgcn_s_sleep(1);
  }
}

#define H 256
#define FH 1024
#define BATCH 32
#define TSEQ 512
#define DSTEPS 64
#define ERING 8

// =====================================================================
// Legacy Phase A GEMM — used only in the bf16-Xg fallback path.
// =====================================================================
__global__ __launch_bounds__(256) void gemm_xw(
    const float* __restrict__ A, const float* __restrict__ W,
    const float* __restrict__ bias, void* __restrict__ Cout, int out_f32)
{
  const int K = 1024, N = 1024;
  __shared__ uint16_t Ah[64 * 40], Al[64 * 40];
  __shared__ uint16_t Wh[64 * 40], Wl[64 * 40];
  const int m0 = blockIdx.x * 64;
  const int n0 = blockIdx.y * 64;
  const int tid = threadIdx.x;
  const int lane = tid & 63, w = tid >> 6;
  const int wm = w & 1, wn = w >> 1;
  const int l15 = lane & 15, q4 = lane >> 4;
  const int ldrow = tid >> 2, ldk = (tid & 3) * 8;

  floatx4 acc[2][2];
  for (int i = 0; i < 2; ++i) for (int j = 0; j < 2; ++j) acc[i][j] = (floatx4){0.f,0.f,0.f,0.f};

  for (int kb = 0; kb < K; kb += 32) {
    float aa[8], ww[8];
    {
      const float4* ap = (const float4*)(A + (size_t)(m0 + ldrow) * K + kb + ldk);
      const float4* wp = (const float4*)(W + (size_t)(n0 + ldrow) * K + kb + ldk);
      *(float4*)(aa) = ap[0]; *(float4*)(aa + 4) = ap[1];
      *(float4*)(ww) = wp[0]; *(float4*)(ww + 4) = wp[1];
    }
    short8 ah, al, wh, wl;
    #pragma unroll
    for (int i = 0; i < 8; ++i) {
      uint16_t h = f2b(aa[i]); ah[i] = (short)h; al[i] = (short)f2b(aa[i] - b2f(h));
      uint16_t g = f2b(ww[i]); wh[i] = (short)g; wl[i] = (short)f2b(ww[i] - b2f(g));
    }
    __syncthreads();
    *(short8*)(Ah + ldrow * 40 + ldk) = ah;
    *(short8*)(Al + ldrow * 40 + ldk) = al;
    *(short8*)(Wh + ldrow * 40 + ldk) = wh;
    *(short8*)(Wl + ldrow * 40 + ldk) = wl;
    __syncthreads();
    short8 afh[2], afl[2], bfh[2], bfl[2];
    #pragma unroll
    for (int mt = 0; mt < 2; ++mt) {
      afh[mt] = *(const short8*)(Ah + (wm * 32 + mt * 16 + l15) * 40 + q4 * 8);
      afl[mt] = *(const short8*)(Al + (wm * 32 + mt * 16 + l15) * 40 + q4 * 8);
    }
    #pragma unroll
    for (int nt = 0; nt < 2; ++nt) {
      bfh[nt] = *(const short8*)(Wh + (wn * 32 + nt * 16 + l15) * 40 + q4 * 8);
      bfl[nt] = *(const short8*)(Wl + (wn * 32 + nt * 16 + l15) * 40 + q4 * 8);
    }
    #pragma unroll
    for (int mt = 0; mt < 2; ++mt)
      #pragma unroll
      for (int nt = 0; nt < 2; ++nt) {
        acc[mt][nt] = mfma16(afh[mt], bfh[nt], acc[mt][nt]);
        acc[mt][nt] = mfma16(afh[mt], bfl[nt], acc[mt][nt]);
        acc[mt][nt] = mfma16(afl[mt], bfh[nt], acc[mt][nt]);
      }
  }
  #pragma unroll
  for (int mt = 0; mt < 2; ++mt)
    #pragma unroll
    for (int nt = 0; nt < 2; ++nt) {
      const int col = n0 + wn * 32 + nt * 16 + l15;
      const float bv = bias[col];
      #pragma unroll
      for (int r = 0; r < 4; ++r) {
        const int row = m0 + wm * 32 + mt * 16 + q4 * 4 + r;
        const float v = acc[mt][nt][r] + bv;
        if (out_f32) ((float*)Cout)[(size_t)row * N + col] = v;
        else         ((uint16_t*)Cout)[(size_t)row * N + col] = f2b(v);
      }
    }
}

// =====================================================================
// FUSED Phase A+B: enc blocks (blockIdx 0..15, dispatched first -> resident
// immediately) walk the latency-bound recurrence while gemm blocks (16..)
// produce Xg tiles on the other CUs. enc is ~98% idle on fabric latency
// (r4 counters: MfmaUtil 0.49, VALUBusy 1.9), so the ~650us of GEMM hides
// entirely under it.
//  - gating: per-(dir,mblock) up-counter. gemm stores its f32 tile via
//    agent-scope atomic stores (write-through -> visible cross-XCD; r0-
//    proven mechanism), __syncthreads (drains vmcnt => stores at coherence
//    point), thread0 fetch_add RELEASE. enc spins ACQUIRE on the flag once
//    per 2 steps (mb = t>>1) before prefetching that tile; acquire's cache
//    invalidate also flushes stale replay lines.
//  - ordering: XgF tiles in ascending m, XgB tiles in DESCENDING m,
//    interleaved (F(k), B(255-k)) so both directions' first-needed tiles
//    are produced first. Production (~2us/mb) outruns consumption
//    (~5.4us/mb) after a short ramp.
//  - deadlock-free by construction: gemm never waits on enc; enc waits on
//    gemm one-way; gemm blocks drain CUs normally.
// enc body itself is the r4-verified barrier-free direct-fragment design.
// =====================================================================
__global__ __launch_bounds__(256, 1) void enc_fused(
    const float* __restrict__ cnn,
    const float* __restrict__ WihF, const float* __restrict__ bF,
    const float* __restrict__ WihB, const float* __restrict__ bB,
    const void* __restrict__ XgF, const void* __restrict__ XgB, int xg_f32,
    const float* __restrict__ WhhF, const float* __restrict__ WhhB,
    uint16_t* __restrict__ hslots,    // [2 dir][ERING][32][256] bf16, poisoned
    uint16_t* __restrict__ hfin, float* __restrict__ cfin,
    unsigned int* __restrict__ xgflags)   // [2][256] up-counters (0 -> 16)
{
  if (blockIdx.x >= 16) {
    // ---------------- GEMM producer branch (fused launch only, f32 out) ----
    const int K = 1024, N = 1024;
    __shared__ uint16_t Ah[64 * 40], Al[64 * 40];
    __shared__ uint16_t Wh[64 * 40], Wl[64 * 40];
    const int bx = (int)blockIdx.x - 16;
    const int kk = bx >> 5, sub = bx & 31;
    const int dirg = sub >> 4, nb = sub & 15;
    const int mb = dirg ? (255 - kk) : kk;
    const float* A    = cnn;
    const float* W    = dirg ? WihB : WihF;
    const float* bias = dirg ? bB : bF;
    uint32_t* Co = (uint32_t*)(dirg ? XgB : XgF);
    const int m0 = mb * 64, n0 = nb * 64;
    const int tid = threadIdx.x;
    const int lane = tid & 63, w = tid >> 6;
    const int wm = w & 1, wn = w >> 1;
    const int l15 = lane & 15, q4 = lane >> 4;
    const int ldrow = tid >> 2, ldk = (tid & 3) * 8;

    floatx4 acc[2][2];
    for (int i = 0; i < 2; ++i) for (int j = 0; j < 2; ++j) acc[i][j] = (floatx4){0.f,0.f,0.f,0.f};

    for (int kb = 0; kb < K; kb += 32) {
      float aa[8], ww[8];
      {
        const float4* ap = (const float4*)(A + (size_t)(m0 + ldrow) * K + kb + ldk);
        const float4* wp = (const float4*)(W + (size_t)(n0 + ldrow) * K + kb + ldk);
        *(float4*)(aa) = ap[0]; *(float4*)(aa + 4) = ap[1];
        *(float4*)(ww) = wp[0]; *(float4*)(ww + 4) = wp[1];
      }
      short8 ah, al, wh, wl;
      #pragma unroll
      for (int i = 0; i < 8; ++i) {
        uint16_t h = f2b(aa[i]); ah[i] = (short)h; al[i] = (short)f2b(aa[i] - b2f(h));
        uint16_t g = f2b(ww[i]); wh[i] = (short)g; wl[i] = (short)f2b(ww[i] - b2f(g));
      }
      __syncthreads();
      *(short8*)(Ah + ldrow * 40 + ldk) = ah;
      *(short8*)(Al + ldrow * 40 + ldk) = al;
      *(short8*)(Wh + ldrow * 40 + ldk) = wh;
      *(short8*)(Wl + ldrow * 40 + ldk) = wl;
      __syncthreads();
      short8 afh[2], afl[2], bfh[2], bfl[2];
      #pragma unroll
      for (int mt = 0; mt < 2; ++mt) {
        afh[mt] = *(const short8*)(Ah + (wm * 32 + mt * 16 + l15) * 40 + q4 * 8);
        afl[mt] = *(const short8*)(Al + (wm * 32 + mt * 16 + l15) * 40 + q4 * 8);
      }
      #pragma unroll
      for (int nt = 0; nt < 2; ++nt) {
        bfh[nt] = *(const short8*)(Wh + (wn * 32 + nt * 16 + l15) * 40 + q4 * 8);
        bfl[nt] = *(const short8*)(Wl + (wn * 32 + nt * 16 + l15) * 40 + q4 * 8);
      }
      #pragma unroll
      for (int mt = 0; mt < 2; ++mt)
        #pragma unroll
        for (int nt = 0; nt < 2; ++nt) {
          acc[mt][nt] = mfma16(afh[mt], bfh[nt], acc[mt][nt]);
          acc[mt][nt] = mfma16(afh[mt], bfl[nt], acc[mt][nt]);
          acc[mt][nt] = mfma16(afl[mt], bfh[nt], acc[mt][nt]);
        }
    }
    #pragma unroll
    for (int mt = 0; mt < 2; ++mt)
      #pragma unroll
      for (int nt = 0; nt < 2; ++nt) {
        const int col = n0 + wn * 32 + nt * 16 + l15;
        const float bv = bias[col];
        #pragma unroll
        for (int r = 0; r < 4; ++r) {
          const int row = m0 + wm * 32 + mt * 16 + q4 * 4 + r;
          union { float f; uint32_t u; } cv; cv.f = acc[mt][nt][r] + bv;
          // write-through (agent scope) so the tile is at the coherence
          // point before the flag release
          __hip_atomic_store(Co + (size_t)row * N + col, cv.u,
                             __ATOMIC_RELAXED, __HIP_MEMORY_SCOPE_AGENT);
        }
      }
    __syncthreads();   // implies vmcnt(0): all tile stores retired
    if (threadIdx.x == 0)
      __hip_atomic_fetch_add(&xgflags[dirg * 256 + mb], 1u,
                             __ATOMIC_RELEASE, __HIP_MEMORY_SCOPE_AGENT);
    return;
  }

  // ---------------- enc branch (r4 body + flag gating) --------------------
  const int d = blockIdx.x >> 3, q = blockIdx.x & 7;
  const void*  Xg  = d ? XgB : XgF;
  const float* Whh = d ? WhhB : WhhF;
  uint16_t* hsl = hslots + d * (ERING * BATCH * H);
  const int jOff = q * 32;
  const int tid = threadIdx.x, lane = tid & 63, w = tid >> 6;
  const int tt = w & 1, nt = w >> 1, l15 = lane & 15, q4 = lane >> 4;
  const int b = nt * 16 + l15;
  const int jg = jOff + tt * 16 + q4 * 4;

  short8 Af[4][8];
  #pragma unroll
  for (int g = 0; g < 4; ++g) {
    const int grow = g * H + jOff + tt * 16 + l15;
    #pragma unroll
    for (int ks = 0; ks < 8; ++ks)
      Af[g][ks] = cvt8(Whh + (size_t)grow * H + ks * 32 + q4 * 8);
  }

  float cc[4] = {0.f, 0.f, 0.f, 0.f};
  union HV { uint16_t u16[4]; u64 v; } hv; hv.v = 0ull;

  int mb_prev = -1;
  auto waitflag = [&](int s2) {
    const int t2 = d ? (TSEQ - 1 - s2) : s2;
    const int mb = t2 >> 1;
    if (mb != mb_prev) {
      const unsigned int* fp = xgflags + d * 256 + mb;
      while (__hip_atomic_load(fp, __ATOMIC_ACQUIRE, __HIP_MEMORY_SCOPE_AGENT) < 16u)
        __builtin_amdgcn_s_sleep(8);
      mb_prev = mb;
    }
  };

  // per-lane Xg gate slice: [(t*B+b)*FH + g*H + jg], g=0..3
  float xvf[16];
  u64   xvb[4];
  auto ldx = [&](int s2) {
    const int t2 = d ? (TSEQ - 1 - s2) : s2;
    const size_t bas = (size_t)(t2 * BATCH + b) * FH + jg;
    if (xg_f32) {
      const float* xp = (const float*)Xg + bas;
      *(float4*)(xvf + 0)  = *(const float4*)(xp);
      *(float4*)(xvf + 4)  = *(const float4*)(xp + H);
      *(float4*)(xvf + 8)  = *(const float4*)(xp + 2 * H);
      *(float4*)(xvf + 12) = *(const float4*)(xp + 3 * H);
    } else {
      const uint16_t* xp = (const uint16_t*)Xg + bas;
      xvb[0] = *(const u64*)(xp);
      xvb[1] = *(const u64*)(xp + H);
      xvb[2] = *(const u64*)(xp + 2 * H);
      xvb[3] = *(const u64*)(xp + 3 * H);
    }
  };
  waitflag(0);
  ldx(0);

  for (int s = 0; s < TSEQ; ++s) {
    floatx4 a0 = {0.f,0.f,0.f,0.f}, a1 = a0, a2 = a0, a3 = a0;
    if (s > 0) {
      u32x4 pol[8];
      const uint16_t* ps = hsl + ((s - 1) & (ERING - 1)) * (BATCH * H) + b * H + q4 * 8;
      poll8f(ps, pol);
      #pragma unroll
      for (int ks = 0; ks < 8; ++ks) {
        short8 bfv = *(short8*)&pol[ks];
        a0 = mfma16(Af[0][ks], bfv, a0);
        a1 = mfma16(Af[1][ks], bfv, a1);
        a2 = mfma16(Af[2][ks], bfv, a2);
        a3 = mfma16(Af[3][ks], bfv, a3);
      }
    }
    #pragma unroll
    for (int r = 0; r < 4; ++r) {
      const float x0 = xg_f32 ? xvf[0 + r]  : b2f((uint16_t)(xvb[0] >> (16 * r)));
      const float x1 = xg_f32 ? xvf[4 + r]  : b2f((uint16_t)(xvb[1] >> (16 * r)));
      const float x2 = xg_f32 ? xvf[8 + r]  : b2f((uint16_t)(xvb[2] >> (16 * r)));
      const float x3 = xg_f32 ? xvf[12 + r] : b2f((uint16_t)(xvb[3] >> (16 * r)));
      const float gi = a0[r] + x0;
      const float gf = a1[r] + x1;
      const float gc = a2[r] + x2;
      const float go = a3[r] + x3;
      const float cn2 = sigm(gf) * cc[r] + sigm(gi) * tanh_f(gc);
      cc[r] = cn2;
      hv.u16[r] = f2b(sigm(go) * tanh_f(cn2));
    }
    st_h64(hsl + (s & (ERING - 1)) * (BATCH * H) + b * H + jg, hv.v);
    if (s >= 6)   // re-poison own slice at distance 6 (r4-verified safe)
      st_h64(hsl + ((s - 6) & (ERING - 1)) * (BATCH * H) + b * H + jg, SENT);
    if (s + 1 < TSEQ) { waitflag(s + 1); ldx(s + 1); }   // gated prefetch
  }
  #pragma unroll
  for (int r = 0; r < 4; ++r) {
    hfin[d * (BATCH * H) + b * H + jg + r] = hv.u16[r];   // kernel boundary
    cfin[d * (BATCH * H) + b * H + jg + r] = cc[r];
  }
}

// =====================================================================
// Phase C: decoder (r4-verified, unchanged)
// =====================================================================
__global__ __launch_bounds__(256, 1) void dec_rnn(
    const float* __restrict__ Wih0, const float* __restrict__ Whh0, const float* __restrict__ bb0,
    const float* __restrict__ Wih1, const float* __restrict__ Whh1, const float* __restrict__ bb1,
    const uint16_t* __restrict__ hfin, const float* __restrict__ cfin,
    uint16_t* __restrict__ h0slots,  // [64][32][256] bf16, poisoned
    uint16_t* __restrict__ h1slots,  // [64][32][256] bf16, poisoned
    float*    __restrict__ h1f)      // [64][32][256] f32 (plain)
{
  const int L = blockIdx.x >> 3, q = blockIdx.x & 7;
  const float* Wih = L ? Wih1 : Wih0;
  const float* Whh = L ? Whh1 : Whh0;
  const float* bs  = L ? bb1 : bb0;
  const int jOff = q * 32;
  const int tid = threadIdx.x, lane = tid & 63, w = tid >> 6;
  const int tt = w & 1, nt = w >> 1, l15 = lane & 15, q4 = lane >> 4;
  const int b = nt * 16 + l15;
  const int jg = jOff + tt * 16 + q4 * 4;

  short8 Af[4][16];
  #pragma unroll
  for (int g = 0; g < 4; ++g) {
    const int grow = g * H + jOff + tt * 16 + l15;
    #pragma unroll
    for (int ks = 0; ks < 8; ++ks) {
      Af[g][ks]     = cvt8(Wih + (size_t)grow * H + ks * 32 + q4 * 8);
      Af[g][8 + ks] = cvt8(Whh + (size_t)grow * H + ks * 32 + q4 * 8);
    }
  }
  float brg[4][4];
  #pragma unroll
  for (int g = 0; g < 4; ++g)
    #pragma unroll
    for (int r = 0; r < 4; ++r)
      brg[g][r] = bs[g * H + jOff + tt * 16 + q4 * 4 + r];

  float cc[4];
  #pragma unroll
  for (int r = 0; r < 4; ++r) cc[r] = cfin[L * (BATCH * H) + b * H + jg + r];

  uint16_t*       hOwn = L ? h1slots : h0slots;
  const uint16_t* hX   = L ? h0slots : h1slots;
  const int fo = b * H + q4 * 8;   // per-lane fragment base (u16 units)
  union HV { uint16_t u16[4]; u64 v; } hv; hv.v = 0ull;

  for (int t = 0; t < DSTEPS; ++t) {
    u32x4 pol[16];   // 0..7 = x frags, 8..15 = own-h frags
    if (t == 0) {
      const uint16_t* ph = hfin + L * (BATCH * H) + fo;   // plain, kernel boundary
      #pragma unroll
      for (int k = 0; k < 8; ++k) pol[8 + k] = *(const u32x4*)(ph + k * 32);
      if (L == 0) {
        #pragma unroll
        for (int k = 0; k < 8; ++k) pol[k] = (u32x4){0u, 0u, 0u, 0u};
      } else {
        poll8f(hX + fo, pol);                             // x = h0[t=0]
      }
    } else {
      const uint16_t* pOwn = hOwn + (size_t)(t - 1) * (BATCH * H) + fo;
      const uint16_t* pX   = L ? (hX + (size_t)t * (BATCH * H) + fo)        // h0[t]
                               : (hX + (size_t)(t - 1) * (BATCH * H) + fo); // h1[t-1]
      poll16f(pX, pOwn, pol, pol + 8);
    }

    floatx4 a0 = {0.f,0.f,0.f,0.f}, a1 = a0, a2 = a0, a3 = a0;
    #pragma unroll
    for (int ks = 0; ks < 16; ++ks) {
      short8 bfv = *(short8*)&pol[ks];
      a0 = mfma16(Af[0][ks], bfv, a0);
      a1 = mfma16(Af[1][ks], bfv, a1);
      a2 = mfma16(Af[2][ks], bfv, a2);
      a3 = mfma16(Af[3][ks], bfv, a3);
    }
    float hval[4];
    #pragma unroll
    for (int r = 0; r < 4; ++r) {
      const float gi = a0[r] + brg[0][r];
      const float gf = a1[r] + brg[1][r];
      const float gc = a2[r] + brg[2][r];
      const float go = a3[r] + brg[3][r];
      const float cn2 = sigm(gf) * cc[r] + sigm(gi) * tanh_f(gc);
      cc[r] = cn2;
      hval[r] = sigm(go) * tanh_f(cn2);
      hv.u16[r] = f2b(hval[r]);
    }
    st_h64(hOwn + (size_t)t * (BATCH * H) + b * H + jg, hv.v);
    if (L == 1) {
      float* df = h1f + (size_t)t * (BATCH * H) + b * H + jg;
      #pragma unroll
      for (int r = 0; r < 4; ++r) df[r] = hval[r];
    }
  }
}

// =====================================================================
// Phase D
// =====================================================================
__global__ __launch_bounds__(256) void out_proj(
    const float* __restrict__ h1f, const float* __restrict__ linW,
    const float* __restrict__ linb, float* __restrict__ out)
{
  const int idx = blockIdx.x * 256 + threadIdx.x;
  if (idx >= DSTEPS * BATCH * 3) return;
  const int v = idx % 3;
  const int tb = idx / 3;
  const float* hrow = h1f + (size_t)tb * H;
  const float* wrow = linW + (size_t)v * H;
  float s = linb[v];
  for (int k = 0; k < H; ++k) s += hrow[k] * wrow[k];
  out[idx] = s;
}

// =====================================================================
extern "C" void kernel_launch(void* const* d_in, const int* in_sizes, int n_in,
                              void* d_out, int out_size, void* d_ws, size_t ws_size,
                              hipStream_t stream) {
  (void)in_sizes; (void)n_in; (void)out_size;
  const float* cnn   = (const float*)d_in[0];
  const float* WihF  = (const float*)d_in[1];
  const float* WhhF  = (const float*)d_in[2];
  const float* bF    = (const float*)d_in[3];
  const float* WihB  = (const float*)d_in[4];
  const float* WhhB  = (const float*)d_in[5];
  const float* bB    = (const float*)d_in[6];
  const float* Wih0  = (const float*)d_in[7];
  const float* Whh0  = (const float*)d_in[8];
  const float* b0    = (const float*)d_in[9];
  const float* Wih1  = (const float*)d_in[10];
  const float* Whh1  = (const float*)d_in[11];
  const float* b1    = (const float*)d_in[12];
  const float* linW  = (const float*)d_in[13];
  const float* linb  = (const float*)d_in[14];

  const size_t XG_ELEMS = (size_t)TSEQ * BATCH * FH;   // 16 Mi elems / dir
  // small region: hslotsE 262144 | h0slots 1 MB | h1slots 1 MB | hfin 32K |
  //               cfin 64K | xgflags 2K
  const size_t SMALL = 2459648;
  const int xg_f32 = (ws_size >= 2 * XG_ELEMS * 4 + SMALL) ? 1 : 0;
  const size_t S = XG_ELEMS * (xg_f32 ? 4 : 2);

  uint8_t* ws = (uint8_t*)d_ws;
  void*     XgF    = (void*)(ws);
  void*     XgB    = (void*)(ws + S);
  float*    h1f    = (float*)(ws + S);                 // overlaps XgB: dead after enc
  uint8_t*  base   = ws + 2 * S;
  uint16_t* hslotsE = (uint16_t*)(base);               // 2*8*8192*2   = 262144
  uint16_t* h0slots = (uint16_t*)(base + 262144);      // 64*8192*2    = 1048576
  uint16_t* h1slots = (uint16_t*)(base + 1310720);     // 1048576  (poison end 2359296)
  uint16_t* hfin    = (uint16_t*)(base + 2359296);     // 32768
  float*    cfin    = (float*)(base + 2392064);        // 65536 (end 2457600)
  unsigned int* xgflags = (unsigned int*)(base + 2457600); // 2*256*4 = 2048

  // sentinel-poison all exchange slots (required every launch, incl. replays)
  hipMemsetAsync(base, 0xAA, 2359296, stream);

  if (xg_f32) {
    hipMemsetAsync(base + 2457600, 0x00, 2048, stream);   // flags = 0 (pending)
    enc_fused<<<16 + 8192, 256, 0, stream>>>(
        cnn, WihF, bF, WihB, bB, XgF, XgB, 1, WhhF, WhhB,
        hslotsE, hfin, cfin, xgflags);
  } else {
    hipMemsetAsync(base + 2457600, 0xFF, 2048, stream);   // flags >= 16 (done)
    gemm_xw<<<dim3(256, 16), 256, 0, stream>>>(cnn, WihF, bF, XgF, 0);
    gemm_xw<<<dim3(256, 16), 256, 0, stream>>>(cnn, WihB, bB, XgB, 0);
    enc_fused<<<16, 256, 0, stream>>>(
        cnn, WihF, bF, WihB, bB, XgF, XgB, 0, WhhF, WhhB,
        hslotsE, hfin, cfin, xgflags);
  }
  dec_rnn<<<16, 256, 0, stream>>>(Wih0, Whh0, b0, Wih1, Whh1, b1,
                                  hfin, cfin, h0slots, h1slots, h1f);
  out_proj<<<24, 256, 0, stream>>>(h1f, linW, linb, (float*)d_out);
}

// Round 6
// 2313.747 us; speedup vs baseline: 1.0678x; 1.0136x over previous
//
#include <hip/hip_runtime.h>
#include <stdint.h>
#include <stddef.h>

// ---------- types / helpers ----------
typedef __attribute__((ext_vector_type(8))) short  short8;   // 8 bf16 (4 VGPRs)
typedef __attribute__((ext_vector_type(4))) float  floatx4;  // MFMA acc
typedef __attribute__((ext_vector_type(4))) unsigned int u32x4; // 16B poll frag
typedef unsigned long long u64;

#define SENT 0xAAAAAAAAAAAAAAAAull   // ws poison pattern = our sentinel

static __device__ __forceinline__ float b2f(uint16_t h) {
  union { uint32_t u; float f; } v; v.u = ((uint32_t)h) << 16; return v.f;
}
static __device__ __forceinline__ uint16_t f2b(float f) {
  union { float f; uint32_t u; } v; v.f = f;
  uint32_t u = v.u;
  uint32_t r = u + 0x7FFFu + ((u >> 16) & 1u);   // RNE
  return (uint16_t)(r >> 16);
}
static __device__ __forceinline__ float sigm(float x)  { return 1.0f / (1.0f + __expf(-x)); }
static __device__ __forceinline__ float tanh_f(float x){ return 1.0f - 2.0f / (1.0f + __expf(2.0f * x)); }

static __device__ __forceinline__ floatx4 mfma16(short8 a, short8 b, floatx4 c) {
  return __builtin_amdgcn_mfma_f32_16x16x32_bf16(a, b, c, 0, 0, 0);
}
static __device__ __forceinline__ short8 cvt8(const float* p) {
  short8 r;
  #pragma unroll
  for (int i = 0; i < 8; ++i) r[i] = (short)f2b(p[i]);
  return r;
}

// ---------- exchange primitives (r3/r4-proven) ----------
static __device__ __forceinline__ void st_h64(uint16_t* p, u64 v) {
  __hip_atomic_store((u64*)p, v, __ATOMIC_RELAXED, __HIP_MEMORY_SCOPE_AGENT);
}
static __device__ __forceinline__ u64 ld_h64(const u64* p) {
  return __hip_atomic_load(p, __ATOMIC_RELAXED, __HIP_MEMORY_SCOPE_AGENT);
}
static __device__ __forceinline__ bool frag_ok(u32x4 v) {
  const u64 lo = ((u64)v[1] << 32) | v[0];
  const u64 hi = ((u64)v[3] << 32) | v[2];
  return (lo != SENT) & (hi != SENT);
}
static __device__ __forceinline__ void ld8x16(const uint16_t* p, u32x4* o) {
  asm volatile(
      "global_load_dwordx4 %0, %8, off sc0 sc1\n\t"
      "global_load_dwordx4 %1, %8, off offset:64 sc0 sc1\n\t"
      "global_load_dwordx4 %2, %8, off offset:128 sc0 sc1\n\t"
      "global_load_dwordx4 %3, %8, off offset:192 sc0 sc1\n\t"
      "global_load_dwordx4 %4, %8, off offset:256 sc0 sc1\n\t"
      "global_load_dwordx4 %5, %8, off offset:320 sc0 sc1\n\t"
      "global_load_dwordx4 %6, %8, off offset:384 sc0 sc1\n\t"
      "global_load_dwordx4 %7, %8, off offset:448 sc0 sc1\n\t"
      "s_waitcnt vmcnt(0)"
      : "=&v"(o[0]), "=&v"(o[1]), "=&v"(o[2]), "=&v"(o[3]),
        "=&v"(o[4]), "=&v"(o[5]), "=&v"(o[6]), "=&v"(o[7])
      : "v"(p)
      : "memory");
}
static __device__ __forceinline__ void ld16x16(const uint16_t* pa, const uint16_t* pb,
                                               u32x4* oa, u32x4* ob) {
  asm volatile(
      "global_load_dwordx4 %0, %16, off sc0 sc1\n\t"
      "global_load_dwordx4 %1, %16, off offset:64 sc0 sc1\n\t"
      "global_load_dwordx4 %2, %16, off offset:128 sc0 sc1\n\t"
      "global_load_dwordx4 %3, %16, off offset:192 sc0 sc1\n\t"
      "global_load_dwordx4 %4, %16, off offset:256 sc0 sc1\n\t"
      "global_load_dwordx4 %5, %16, off offset:320 sc0 sc1\n\t"
      "global_load_dwordx4 %6, %16, off offset:384 sc0 sc1\n\t"
      "global_load_dwordx4 %7, %16, off offset:448 sc0 sc1\n\t"
      "global_load_dwordx4 %8, %17, off sc0 sc1\n\t"
      "global_load_dwordx4 %9, %17, off offset:64 sc0 sc1\n\t"
      "global_load_dwordx4 %10, %17, off offset:128 sc0 sc1\n\t"
      "global_load_dwordx4 %11, %17, off offset:192 sc0 sc1\n\t"
      "global_load_dwordx4 %12, %17, off offset:256 sc0 sc1\n\t"
      "global_load_dwordx4 %13, %17, off offset:320 sc0 sc1\n\t"
      "global_load_dwordx4 %14, %17, off offset:384 sc0 sc1\n\t"
      "global_load_dwordx4 %15, %17, off offset:448 sc0 sc1\n\t"
      "s_waitcnt vmcnt(0)"
      : "=&v"(oa[0]), "=&v"(oa[1]), "=&v"(oa[2]), "=&v"(oa[3]),
        "=&v"(oa[4]), "=&v"(oa[5]), "=&v"(oa[6]), "=&v"(oa[7]),
        "=&v"(ob[0]), "=&v"(ob[1]), "=&v"(ob[2]), "=&v"(ob[3]),
        "=&v"(ob[4]), "=&v"(ob[5]), "=&v"(ob[6]), "=&v"(ob[7])
      : "v"(pa), "v"(pb)
      : "memory");
}
// 16 consecutive u32 flags, one wait
static __device__ __forceinline__ void ld4x16f(const unsigned int* p, u32x4* o) {
  asm volatile(
      "global_load_dwordx4 %0, %4, off sc0 sc1\n\t"
      "global_load_dwordx4 %1, %4, off offset:16 sc0 sc1\n\t"
      "global_load_dwordx4 %2, %4, off offset:32 sc0 sc1\n\t"
      "global_load_dwordx4 %3, %4, off offset:48 sc0 sc1\n\t"
      "s_waitcnt vmcnt(0)"
      : "=&v"(o[0]), "=&v"(o[1]), "=&v"(o[2]), "=&v"(o[3])
      : "v"(p)
      : "memory");
}
static __device__ __forceinline__ void valve8(const uint16_t* p, u32x4* o) {
  const u64* q = (const u64*)p;
  #pragma unroll
  for (int k = 0; k < 8; ++k) {
    u64 a = ld_h64(q + k * 8), c = ld_h64(q + k * 8 + 1);
    o[k][0] = (unsigned)a; o[k][1] = (unsigned)(a >> 32);
    o[k][2] = (unsigned)c; o[k][3] = (unsigned)(c >> 32);
  }
}
static __device__ __forceinline__ void poll8f(const uint16_t* p, u32x4* o) {
  int it = 0;
  for (;;) {
    if ((++it & 1023) == 0) valve8(p, o); else ld8x16(p, o);
    bool ok = true;
    #pragma unroll
    for (int k = 0; k < 8; ++k) ok &= frag_ok(o[k]);
    if (ok) break;
    __builtin_amdgcn_s_sleep(1);
  }
}
static __device__ __forceinline__ void poll16f(const uint16_t* pa, const uint16_t* pb,
                                               u32x4* oa, u32x4* ob) {
  int it = 0;
  for (;;) {
    if ((++it & 1023) == 0) { valve8(pa, oa); valve8(pb, ob); }
    else ld16x16(pa, pb, oa, ob);
    bool ok = true;
    #pragma unroll
    for (int k = 0; k < 8; ++k) ok &= frag_ok(oa[k]) & frag_ok(ob[k]);
    if (ok) break;
    __builtin_amdgcn_s_sleep(1);
  }
}

#define H 256
#define FH 1024
#define BATCH 32
#define TSEQ 512
#define DSTEPS 64
#define ERING 8

// =====================================================================
// Legacy Phase A GEMM — used only in the bf16-Xg fallback path.
// =====================================================================
__global__ __launch_bounds__(256) void gemm_xw(
    const float* __restrict__ A, const float* __restrict__ W,
    const float* __restrict__ bias, void* __restrict__ Cout, int out_f32)
{
  const int K = 1024, N = 1024;
  __shared__ uint16_t Ah[64 * 40], Al[64 * 40];
  __shared__ uint16_t Wh[64 * 40], Wl[64 * 40];
  const int m0 = blockIdx.x * 64;
  const int n0 = blockIdx.y * 64;
  const int tid = threadIdx.x;
  const int lane = tid & 63, w = tid >> 6;
  const int wm = w & 1, wn = w >> 1;
  const int l15 = lane & 15, q4 = lane >> 4;
  const int ldrow = tid >> 2, ldk = (tid & 3) * 8;

  floatx4 acc[2][2];
  for (int i = 0; i < 2; ++i) for (int j = 0; j < 2; ++j) acc[i][j] = (floatx4){0.f,0.f,0.f,0.f};

  for (int kb = 0; kb < K; kb += 32) {
    float aa[8], ww[8];
    {
      const float4* ap = (const float4*)(A + (size_t)(m0 + ldrow) * K + kb + ldk);
      const float4* wp = (const float4*)(W + (size_t)(n0 + ldrow) * K + kb + ldk);
      *(float4*)(aa) = ap[0]; *(float4*)(aa + 4) = ap[1];
      *(float4*)(ww) = wp[0]; *(float4*)(ww + 4) = wp[1];
    }
    short8 ah, al, wh, wl;
    #pragma unroll
    for (int i = 0; i < 8; ++i) {
      uint16_t h = f2b(aa[i]); ah[i] = (short)h; al[i] = (short)f2b(aa[i] - b2f(h));
      uint16_t g = f2b(ww[i]); wh[i] = (short)g; wl[i] = (short)f2b(ww[i] - b2f(g));
    }
    __syncthreads();
    *(short8*)(Ah + ldrow * 40 + ldk) = ah;
    *(short8*)(Al + ldrow * 40 + ldk) = al;
    *(short8*)(Wh + ldrow * 40 + ldk) = wh;
    *(short8*)(Wl + ldrow * 40 + ldk) = wl;
    __syncthreads();
    short8 afh[2], afl[2], bfh[2], bfl[2];
    #pragma unroll
    for (int mt = 0; mt < 2; ++mt) {
      afh[mt] = *(const short8*)(Ah + (wm * 32 + mt * 16 + l15) * 40 + q4 * 8);
      afl[mt] = *(const short8*)(Al + (wm * 32 + mt * 16 + l15) * 40 + q4 * 8);
    }
    #pragma unroll
    for (int nt = 0; nt < 2; ++nt) {
      bfh[nt] = *(const short8*)(Wh + (wn * 32 + nt * 16 + l15) * 40 + q4 * 8);
      bfl[nt] = *(const short8*)(Wl + (wn * 32 + nt * 16 + l15) * 40 + q4 * 8);
    }
    #pragma unroll
    for (int mt = 0; mt < 2; ++mt)
      #pragma unroll
      for (int nt = 0; nt < 2; ++nt) {
        acc[mt][nt] = mfma16(afh[mt], bfh[nt], acc[mt][nt]);
        acc[mt][nt] = mfma16(afh[mt], bfl[nt], acc[mt][nt]);
        acc[mt][nt] = mfma16(afl[mt], bfh[nt], acc[mt][nt]);
      }
  }
  #pragma unroll
  for (int mt = 0; mt < 2; ++mt)
    #pragma unroll
    for (int nt = 0; nt < 2; ++nt) {
      const int col = n0 + wn * 32 + nt * 16 + l15;
      const float bv = bias[col];
      #pragma unroll
      for (int r = 0; r < 4; ++r) {
        const int row = m0 + wm * 32 + mt * 16 + q4 * 4 + r;
        const float v = acc[mt][nt][r] + bv;
        if (out_f32) ((float*)Cout)[(size_t)row * N + col] = v;
        else         ((uint16_t*)Cout)[(size_t)row * N + col] = f2b(v);
      }
    }
}

// =====================================================================
// FUSED Phase A+B (r5 structure + two fixes from r5 post-mortem):
//  FIX 1 — flag lookahead: r5 did one ACQUIRE flag load per mb (256 serial
//    fabric RTs ~= the observed +256us on enc's critical path). Now: check
//    a 16-flag window with 4 batched dwordx4 loads + ONE vmcnt + ONE
//    acquire fence; advance 16 mbs (32 steps) per check. Window clamped to
//    [240..255] near the tail (no OOB); flags are up-counters so including
//    already-consumed indices is monotone-safe. Miss => r5's per-flag
//    acquire spin (ramp only).
//  FIX 2 — LDS floor 86016B (>80KB) forces 1 block/CU chip-wide so GEMM
//    blocks can never co-reside with enc blocks and steal SIMD slots
//    (enc used 0 LDS in r5 -> 8-wave cap allowed a GEMM block alongside).
//    GEMM per-block gets slower (4 waves/CU) but production retains ~4x
//    margin over enc consumption.
// Everything else (gating protocol, store/flag release, tile ordering,
// enc body) is r5-verified and unchanged.
// =====================================================================
__global__ __launch_bounds__(256, 1) void enc_fused(
    const float* __restrict__ cnn,
    const float* __restrict__ WihF, const float* __restrict__ bF,
    const float* __restrict__ WihB, const float* __restrict__ bB,
    const void* __restrict__ XgF, const void* __restrict__ XgB, int xg_f32,
    const float* __restrict__ WhhF, const float* __restrict__ WhhB,
    uint16_t* __restrict__ hslots,    // [2 dir][ERING][32][256] bf16, poisoned
    uint16_t* __restrict__ hfin, float* __restrict__ cfin,
    unsigned int* __restrict__ xgflags)   // [2][256] up-counters (0 -> 16)
{
  // LDS floor: 20480 (gemm arrays) + 65536 (pad) = 86016 > 80KB => 1 block/CU.
  __shared__ uint8_t ldspad[65536];
  if (xg_f32 == 31415) ((volatile uint8_t*)ldspad)[threadIdx.x] = 1;  // keep-alive

  if (blockIdx.x >= 16) {
    // ---------------- GEMM producer branch (fused launch only, f32 out) ----
    const int K = 1024, N = 1024;
    __shared__ uint16_t Ah[64 * 40], Al[64 * 40];
    __shared__ uint16_t Wh[64 * 40], Wl[64 * 40];
    const int bx = (int)blockIdx.x - 16;
    const int kk = bx >> 5, sub = bx & 31;
    const int dirg = sub >> 4, nb = sub & 15;
    const int mb = dirg ? (255 - kk) : kk;
    const float* A    = cnn;
    const float* W    = dirg ? WihB : WihF;
    const float* bias = dirg ? bB : bF;
    uint32_t* Co = (uint32_t*)(dirg ? XgB : XgF);
    const int m0 = mb * 64, n0 = nb * 64;
    const int tid = threadIdx.x;
    const int lane = tid & 63, w = tid >> 6;
    const int wm = w & 1, wn = w >> 1;
    const int l15 = lane & 15, q4 = lane >> 4;
    const int ldrow = tid >> 2, ldk = (tid & 3) * 8;

    floatx4 acc[2][2];
    for (int i = 0; i < 2; ++i) for (int j = 0; j < 2; ++j) acc[i][j] = (floatx4){0.f,0.f,0.f,0.f};

    for (int kb = 0; kb < K; kb += 32) {
      float aa[8], ww[8];
      {
        const float4* ap = (const float4*)(A + (size_t)(m0 + ldrow) * K + kb + ldk);
        const float4* wp = (const float4*)(W + (size_t)(n0 + ldrow) * K + kb + ldk);
        *(float4*)(aa) = ap[0]; *(float4*)(aa + 4) = ap[1];
        *(float4*)(ww) = wp[0]; *(float4*)(ww + 4) = wp[1];
      }
      short8 ah, al, wh, wl;
      #pragma unroll
      for (int i = 0; i < 8; ++i) {
        uint16_t h = f2b(aa[i]); ah[i] = (short)h; al[i] = (short)f2b(aa[i] - b2f(h));
        uint16_t g = f2b(ww[i]); wh[i] = (short)g; wl[i] = (short)f2b(ww[i] - b2f(g));
      }
      __syncthreads();
      *(short8*)(Ah + ldrow * 40 + ldk) = ah;
      *(short8*)(Al + ldrow * 40 + ldk) = al;
      *(short8*)(Wh + ldrow * 40 + ldk) = wh;
      *(short8*)(Wl + ldrow * 40 + ldk) = wl;
      __syncthreads();
      short8 afh[2], afl[2], bfh[2], bfl[2];
      #pragma unroll
      for (int mt = 0; mt < 2; ++mt) {
        afh[mt] = *(const short8*)(Ah + (wm * 32 + mt * 16 + l15) * 40 + q4 * 8);
        afl[mt] = *(const short8*)(Al + (wm * 32 + mt * 16 + l15) * 40 + q4 * 8);
      }
      #pragma unroll
      for (int nt = 0; nt < 2; ++nt) {
        bfh[nt] = *(const short8*)(Wh + (wn * 32 + nt * 16 + l15) * 40 + q4 * 8);
        bfl[nt] = *(const short8*)(Wl + (wn * 32 + nt * 16 + l15) * 40 + q4 * 8);
      }
      #pragma unroll
      for (int mt = 0; mt < 2; ++mt)
        #pragma unroll
        for (int nt = 0; nt < 2; ++nt) {
          acc[mt][nt] = mfma16(afh[mt], bfh[nt], acc[mt][nt]);
          acc[mt][nt] = mfma16(afh[mt], bfl[nt], acc[mt][nt]);
          acc[mt][nt] = mfma16(afl[mt], bfh[nt], acc[mt][nt]);
        }
    }
    #pragma unroll
    for (int mt = 0; mt < 2; ++mt)
      #pragma unroll
      for (int nt = 0; nt < 2; ++nt) {
        const int col = n0 + wn * 32 + nt * 16 + l15;
        const float bv = bias[col];
        #pragma unroll
        for (int r = 0; r < 4; ++r) {
          const int row = m0 + wm * 32 + mt * 16 + q4 * 4 + r;
          union { float f; uint32_t u; } cv; cv.f = acc[mt][nt][r] + bv;
          // write-through (agent scope): tile at coherence point before release
          __hip_atomic_store(Co + (size_t)row * N + col, cv.u,
                             __ATOMIC_RELAXED, __HIP_MEMORY_SCOPE_AGENT);
        }
      }
    __syncthreads();   // implies vmcnt(0): all tile stores retired
    if (threadIdx.x == 0)
      __hip_atomic_fetch_add(&xgflags[dirg * 256 + mb], 1u,
                             __ATOMIC_RELEASE, __HIP_MEMORY_SCOPE_AGENT);
    return;
  }

  // ---------------- enc branch (r4 body + lookahead flag gating) ----------
  const int d = blockIdx.x >> 3, q = blockIdx.x & 7;
  const void*  Xg  = d ? XgB : XgF;
  const float* Whh = d ? WhhB : WhhF;
  uint16_t* hsl = hslots + d * (ERING * BATCH * H);
  const int jOff = q * 32;
  const int tid = threadIdx.x, lane = tid & 63, w = tid >> 6;
  const int tt = w & 1, nt = w >> 1, l15 = lane & 15, q4 = lane >> 4;
  const int b = nt * 16 + l15;
  const int jg = jOff + tt * 16 + q4 * 4;

  short8 Af[4][8];
  #pragma unroll
  for (int g = 0; g < 4; ++g) {
    const int grow = g * H + jOff + tt * 16 + l15;
    #pragma unroll
    for (int ks = 0; ks < 8; ++ks)
      Af[g][ks] = cvt8(Whh + (size_t)grow * H + ks * 32 + q4 * 8);
  }

  float cc[4] = {0.f, 0.f, 0.f, 0.f};
  union HV { uint16_t u16[4]; u64 v; } hv; hv.v = 0ull;

  // Consumption-order flag gating. idx k = s>>1 for BOTH dirs
  // (F: mb = k ascending; B: mb = 255-k). done = highest consumable idx.
  int done = -1;
  auto waitidx = [&](int k) {
    if (k <= done) return;
    const int bi = k < 240 ? k : 240;                 // window = idx bi..bi+15
    const unsigned int* fb = xgflags + d * 256 + (d ? (240 - bi) : bi);
    u32x4 fv[4];
    ld4x16f(fb, fv);
    bool all = true;
    #pragma unroll
    for (int i = 0; i < 4; ++i)
      #pragma unroll
      for (int j = 0; j < 4; ++j) all &= (fv[i][j] >= 16u);
    if (all) {
      __builtin_amdgcn_fence(__ATOMIC_ACQUIRE, "agent");   // invalidate caches
      done = bi + 15;
      return;
    }
    const unsigned int* fk = xgflags + d * 256 + (d ? (255 - k) : k);
    while (__hip_atomic_load(fk, __ATOMIC_ACQUIRE, __HIP_MEMORY_SCOPE_AGENT) < 16u)
      __builtin_amdgcn_s_sleep(8);
    done = k;
  };

  // per-lane Xg gate slice: [(t*B+b)*FH + g*H + jg], g=0..3
  float xvf[16];
  u64   xvb[4];
  auto ldx = [&](int s2) {
    const int t2 = d ? (TSEQ - 1 - s2) : s2;
    const size_t bas = (size_t)(t2 * BATCH + b) * FH + jg;
    if (xg_f32) {
      const float* xp = (const float*)Xg + bas;
      *(float4*)(xvf + 0)  = *(const float4*)(xp);
      *(float4*)(xvf + 4)  = *(const float4*)(xp + H);
      *(float4*)(xvf + 8)  = *(const float4*)(xp + 2 * H);
      *(float4*)(xvf + 12) = *(const float4*)(xp + 3 * H);
    } else {
      const uint16_t* xp = (const uint16_t*)Xg + bas;
      xvb[0] = *(const u64*)(xp);
      xvb[1] = *(const u64*)(xp + H);
      xvb[2] = *(const u64*)(xp + 2 * H);
      xvb[3] = *(const u64*)(xp + 3 * H);
    }
  };
  waitidx(0);
  ldx(0);

  for (int s = 0; s < TSEQ; ++s) {
    floatx4 a0 = {0.f,0.f,0.f,0.f}, a1 = a0, a2 = a0, a3 = a0;
    if (s > 0) {
      u32x4 pol[8];
      const uint16_t* ps = hsl + ((s - 1) & (ERING - 1)) * (BATCH * H) + b * H + q4 * 8;
      poll8f(ps, pol);
      #pragma unroll
      for (int ks = 0; ks < 8; ++ks) {
        short8 bfv = *(short8*)&pol[ks];
        a0 = mfma16(Af[0][ks], bfv, a0);
        a1 = mfma16(Af[1][ks], bfv, a1);
        a2 = mfma16(Af[2][ks], bfv, a2);
        a3 = mfma16(Af[3][ks], bfv, a3);
      }
    }
    #pragma unroll
    for (int r = 0; r < 4; ++r) {
      const float x0 = xg_f32 ? xvf[0 + r]  : b2f((uint16_t)(xvb[0] >> (16 * r)));
      const float x1 = xg_f32 ? xvf[4 + r]  : b2f((uint16_t)(xvb[1] >> (16 * r)));
      const float x2 = xg_f32 ? xvf[8 + r]  : b2f((uint16_t)(xvb[2] >> (16 * r)));
      const float x3 = xg_f32 ? xvf[12 + r] : b2f((uint16_t)(xvb[3] >> (16 * r)));
      const float gi = a0[r] + x0;
      const float gf = a1[r] + x1;
      const float gc = a2[r] + x2;
      const float go = a3[r] + x3;
      const float cn2 = sigm(gf) * cc[r] + sigm(gi) * tanh_f(gc);
      cc[r] = cn2;
      hv.u16[r] = f2b(sigm(go) * tanh_f(cn2));
    }
    st_h64(hsl + (s & (ERING - 1)) * (BATCH * H) + b * H + jg, hv.v);
    if (s >= 6)   // re-poison own slice at distance 6 (r4-verified safe)
      st_h64(hsl + ((s - 6) & (ERING - 1)) * (BATCH * H) + b * H + jg, SENT);
    if (s + 1 < TSEQ) { waitidx((s + 1) >> 1); ldx(s + 1); }   // gated prefetch
  }
  #pragma unroll
  for (int r = 0; r < 4; ++r) {
    hfin[d * (BATCH * H) + b * H + jg + r] = hv.u16[r];   // kernel boundary
    cfin[d * (BATCH * H) + b * H + jg + r] = cc[r];
  }
}

// =====================================================================
// Phase C: decoder (r4-verified, unchanged)
// =====================================================================
__global__ __launch_bounds__(256, 1) void dec_rnn(
    const float* __restrict__ Wih0, const float* __restrict__ Whh0, const float* __restrict__ bb0,
    const float* __restrict__ Wih1, const float* __restrict__ Whh1, const float* __restrict__ bb1,
    const uint16_t* __restrict__ hfin, const float* __restrict__ cfin,
    uint16_t* __restrict__ h0slots,  // [64][32][256] bf16, poisoned
    uint16_t* __restrict__ h1slots,  // [64][32][256] bf16, poisoned
    float*    __restrict__ h1f)      // [64][32][256] f32 (plain)
{
  const int L = blockIdx.x >> 3, q = blockIdx.x & 7;
  const float* Wih = L ? Wih1 : Wih0;
  const float* Whh = L ? Whh1 : Whh0;
  const float* bs  = L ? bb1 : bb0;
  const int jOff = q * 32;
  const int tid = threadIdx.x, lane = tid & 63, w = tid >> 6;
  const int tt = w & 1, nt = w >> 1, l15 = lane & 15, q4 = lane >> 4;
  const int b = nt * 16 + l15;
  const int jg = jOff + tt * 16 + q4 * 4;

  short8 Af[4][16];
  #pragma unroll
  for (int g = 0; g < 4; ++g) {
    const int grow = g * H + jOff + tt * 16 + l15;
    #pragma unroll
    for (int ks = 0; ks < 8; ++ks) {
      Af[g][ks]     = cvt8(Wih + (size_t)grow * H + ks * 32 + q4 * 8);
      Af[g][8 + ks] = cvt8(Whh + (size_t)grow * H + ks * 32 + q4 * 8);
    }
  }
  float brg[4][4];
  #pragma unroll
  for (int g = 0; g < 4; ++g)
    #pragma unroll
    for (int r = 0; r < 4; ++r)
      brg[g][r] = bs[g * H + jOff + tt * 16 + q4 * 4 + r];

  float cc[4];
  #pragma unroll
  for (int r = 0; r < 4; ++r) cc[r] = cfin[L * (BATCH * H) + b * H + jg + r];

  uint16_t*       hOwn = L ? h1slots : h0slots;
  const uint16_t* hX   = L ? h0slots : h1slots;
  const int fo = b * H + q4 * 8;   // per-lane fragment base (u16 units)
  union HV { uint16_t u16[4]; u64 v; } hv; hv.v = 0ull;

  for (int t = 0; t < DSTEPS; ++t) {
    u32x4 pol[16];   // 0..7 = x frags, 8..15 = own-h frags
    if (t == 0) {
      const uint16_t* ph = hfin + L * (BATCH * H) + fo;   // plain, kernel boundary
      #pragma unroll
      for (int k = 0; k < 8; ++k) pol[8 + k] = *(const u32x4*)(ph + k * 32);
      if (L == 0) {
        #pragma unroll
        for (int k = 0; k < 8; ++k) pol[k] = (u32x4){0u, 0u, 0u, 0u};
      } else {
        poll8f(hX + fo, pol);                             // x = h0[t=0]
      }
    } else {
      const uint16_t* pOwn = hOwn + (size_t)(t - 1) * (BATCH * H) + fo;
      const uint16_t* pX   = L ? (hX + (size_t)t * (BATCH * H) + fo)        // h0[t]
                               : (hX + (size_t)(t - 1) * (BATCH * H) + fo); // h1[t-1]
      poll16f(pX, pOwn, pol, pol + 8);
    }

    floatx4 a0 = {0.f,0.f,0.f,0.f}, a1 = a0, a2 = a0, a3 = a0;
    #pragma unroll
    for (int ks = 0; ks < 16; ++ks) {
      short8 bfv = *(short8*)&pol[ks];
      a0 = mfma16(Af[0][ks], bfv, a0);
      a1 = mfma16(Af[1][ks], bfv, a1);
      a2 = mfma16(Af[2][ks], bfv, a2);
      a3 = mfma16(Af[3][ks], bfv, a3);
    }
    float hval[4];
    #pragma unroll
    for (int r = 0; r < 4; ++r) {
      const float gi = a0[r] + brg[0][r];
      const float gf = a1[r] + brg[1][r];
      const float gc = a2[r] + brg[2][r];
      const float go = a3[r] + brg[3][r];
      const float cn2 = sigm(gf) * cc[r] + sigm(gi) * tanh_f(gc);
      cc[r] = cn2;
      hval[r] = sigm(go) * tanh_f(cn2);
      hv.u16[r] = f2b(hval[r]);
    }
    st_h64(hOwn + (size_t)t * (BATCH * H) + b * H + jg, hv.v);
    if (L == 1) {
      float* df = h1f + (size_t)t * (BATCH * H) + b * H + jg;
      #pragma unroll
      for (int r = 0; r < 4; ++r) df[r] = hval[r];
    }
  }
}

// =====================================================================
// Phase D
// =====================================================================
__global__ __launch_bounds__(256) void out_proj(
    const float* __restrict__ h1f, const float* __restrict__ linW,
    const float* __restrict__ linb, float* __restrict__ out)
{
  const int idx = blockIdx.x * 256 + threadIdx.x;
  if (idx >= DSTEPS * BATCH * 3) return;
  const int v = idx % 3;
  const int tb = idx / 3;
  const float* hrow = h1f + (size_t)tb * H;
  const float* wrow = linW + (size_t)v * H;
  float s = linb[v];
  for (int k = 0; k < H; ++k) s += hrow[k] * wrow[k];
  out[idx] = s;
}

// =====================================================================
extern "C" void kernel_launch(void* const* d_in, const int* in_sizes, int n_in,
                              void* d_out, int out_size, void* d_ws, size_t ws_size,
                              hipStream_t stream) {
  (void)in_sizes; (void)n_in; (void)out_size;
  const float* cnn   = (const float*)d_in[0];
  const float* WihF  = (const float*)d_in[1];
  const float* WhhF  = (const float*)d_in[2];
  const float* bF    = (const float*)d_in[3];
  const float* WihB  = (const float*)d_in[4];
  const float* WhhB  = (const float*)d_in[5];
  const float* bB    = (const float*)d_in[6];
  const float* Wih0  = (const float*)d_in[7];
  const float* Whh0  = (const float*)d_in[8];
  const float* b0    = (const float*)d_in[9];
  const float* Wih1  = (const float*)d_in[10];
  const float* Whh1  = (const float*)d_in[11];
  const float* b1    = (const float*)d_in[12];
  const float* linW  = (const float*)d_in[13];
  const float* linb  = (const float*)d_in[14];

  const size_t XG_ELEMS = (size_t)TSEQ * BATCH * FH;   // 16 Mi elems / dir
  // small region: hslotsE 262144 | h0slots 1 MB | h1slots 1 MB | hfin 32K |
  //               cfin 64K | xgflags 2K
  const size_t SMALL = 2459648;
  const int xg_f32 = (ws_size >= 2 * XG_ELEMS * 4 + SMALL) ? 1 : 0;
  const size_t S = XG_ELEMS * (xg_f32 ? 4 : 2);

  uint8_t* ws = (uint8_t*)d_ws;
  void*     XgF    = (void*)(ws);
  void*     XgB    = (void*)(ws + S);
  float*    h1f    = (float*)(ws + S);                 // overlaps XgB: dead after enc
  uint8_t*  base   = ws + 2 * S;
  uint16_t* hslotsE = (uint16_t*)(base);               // 2*8*8192*2   = 262144
  uint16_t* h0slots = (uint16_t*)(base + 262144);      // 64*8192*2    = 1048576
  uint16_t* h1slots = (uint16_t*)(base + 1310720);     // 1048576  (poison end 2359296)
  uint16_t* hfin    = (uint16_t*)(base + 2359296);     // 32768
  float*    cfin    = (float*)(base + 2392064);        // 65536 (end 2457600)
  unsigned int* xgflags = (unsigned int*)(base + 2457600); // 2*256*4 = 2048

  // sentinel-poison all exchange slots (required every launch, incl. replays)
  hipMemsetAsync(base, 0xAA, 2359296, stream);

  if (xg_f32) {
    hipMemsetAsync(base + 2457600, 0x00, 2048, stream);   // flags = 0 (pending)
    enc_fused<<<16 + 8192, 256, 0, stream>>>(
        cnn, WihF, bF, WihB, bB, XgF, XgB, 1, WhhF, WhhB,
        hslotsE, hfin, cfin, xgflags);
  } else {
    hipMemsetAsync(base + 2457600, 0xFF, 2048, stream);   // flags >= 16 (done)
    gemm_xw<<<dim3(256, 16), 256, 0, stream>>>(cnn, WihF, bF, XgF, 0);
    gemm_xw<<<dim3(256, 16), 256, 0, stream>>>(cnn, WihB, bB, XgB, 0);
    enc_fused<<<16, 256, 0, stream>>>(
        cnn, WihF, bF, WihB, bB, XgF, XgB, 0, WhhF, WhhB,
        hslotsE, hfin, cfin, xgflags);
  }
  dec_rnn<<<16, 256, 0, stream>>>(Wih0, Whh0, b0, Wih1, Whh1, b1,
                                  hfin, cfin, h0slots, h1slots, h1f);
  out_proj<<<24, 256, 0, stream>>>(h1f, linW, linb, (float*)d_out);
}